// Round 8
// baseline (207.785 us; speedup 1.0000x reference)
//
#include <hip/hip_runtime.h>
#include <hip/hip_bf16.h>

typedef unsigned short u16;
typedef __attribute__((ext_vector_type(8))) __bf16 bf16x8;
typedef __attribute__((ext_vector_type(8))) unsigned short u16x8;
typedef __attribute__((ext_vector_type(4))) float f32x4;

#define NTOK 32768
#define XLDA 1152           // xu row stride: 1024 x-cols + 128 u-cols
#define WS_XU  0            // u16[NTOK*1152]            = 75,497,472 B
#define WS_WP  75497472     // u16[1024*1152] packed B^T =  2,359,296 B
#define WS_W1T 77856768     // u16[128*1024]  packed A-mats = 262,144 B

static __device__ __forceinline__ u16 f2bf(float f) {
  __hip_bfloat16 h = __float2bfloat16(f);
  return __builtin_bit_cast(u16, h);
}

#define GLOAD_LDS16(g, l)                                                     \
  __builtin_amdgcn_global_load_lds(                                           \
      (const __attribute__((address_space(1))) void*)(g),                     \
      (__attribute__((address_space(3))) void*)(l), 16, 0, 0)

// ---- pack all weight matrices to bf16 in [N][K] (k-contiguous) layout ----
// W1t rows: 0..15 shared_A, 16..111 routed_A, rest 0 (u-cols >=112 are zeroed).
__global__ __launch_bounds__(256) void pack_weights(
    const float* __restrict__ baseW, const float* __restrict__ sharedA,
    const float* __restrict__ sharedB, const float* __restrict__ routedA,
    const float* __restrict__ routedB,
    u16* __restrict__ Wp, u16* __restrict__ W1t) {
  int idx = blockIdx.x * 256 + threadIdx.x;
  const int NWP = 1024 * 1152;
  if (idx < NWP) {
    int o = idx / 1152, k = idx - o * 1152;
    float v;
    if (k < 1024)      v = baseW[o * 1024 + k];
    else if (k < 1040) v = sharedB[o * 16 + (k - 1024)];
    else if (k < 1136) { int c = k - 1040; v = routedB[((c >> 4) * 1024 + o) * 16 + (c & 15)]; }
    else               v = 0.0f;
    Wp[idx] = f2bf(v);
  } else {
    int j = idx - NWP;            // 0 .. 131071
    int n = j >> 10, k = j & 1023;
    float v;
    if (n < 16)       v = sharedA[n * 1024 + k];
    else if (n < 112) v = routedA[(n - 16) * 1024 + k];
    else              v = 0.0f;
    W1t[j] = f2bf(v);
  }
}

// ==== wave-autonomous: convert + fp32 router + u-MFMA, ZERO barriers/LDS ====
// 512 blocks x 256 thr; wave w owns 16 tokens. Lane (fr=lane&15, fq=lane>>4)
// loads x in A-frag layout directly; B-frags from W1t global (L1/L2-resident);
// router fp32 VALU from global rW (L1-resident) + shfl reduce; top-2 per lane;
// wsp redistributed by shfl; e = n-1 is compile-time (no runtime reg index).
__global__ __launch_bounds__(256) void fuse_wave(
    const float* __restrict__ x, const float* __restrict__ rW,
    const float* __restrict__ rB, const u16* __restrict__ W1t,
    u16* __restrict__ xu) {
  const int tid = threadIdx.x, lane = tid & 63, wid = tid >> 6;
  const int fr = lane & 15, fq = lane >> 4;
  const int T0 = (blockIdx.x * 4 + wid) * 16;

  float lp[6];
  #pragma unroll
  for (int e = 0; e < 6; ++e) lp[e] = 0.f;
  f32x4 acc[8];
  #pragma unroll
  for (int n = 0; n < 8; ++n) acc[n] = f32x4{0.f, 0.f, 0.f, 0.f};

  const float* xrow  = x  + (size_t)(T0 + fr) * 1024 + fq * 8;
  u16*         xurow = xu + (size_t)(T0 + fr) * XLDA + fq * 8;
  const u16*   wbase = W1t + (size_t)fr * 1024 + fq * 8;
  const float* rwb   = rW + fq * 8;

  // register prefetch depth 1 (x is the only HBM-cold stream)
  float4 c00 = *(const float4*)(xrow + 0);
  float4 c01 = *(const float4*)(xrow + 4);
  float4 c10 = *(const float4*)(xrow + 32);
  float4 c11 = *(const float4*)(xrow + 36);

  for (int kt = 0; kt < 16; ++kt) {
    const int kn = (kt < 15 ? (kt + 1) * 64 : 15 * 64);
    float4 n00 = *(const float4*)(xrow + kn + 0);
    float4 n01 = *(const float4*)(xrow + kn + 4);
    float4 n10 = *(const float4*)(xrow + kn + 32);
    float4 n11 = *(const float4*)(xrow + kn + 36);

    // convert current window -> bf16, store x-cols, keep as A-frags
    u16x8 o0, o1;
    o0[0] = f2bf(c00.x); o0[1] = f2bf(c00.y); o0[2] = f2bf(c00.z); o0[3] = f2bf(c00.w);
    o0[4] = f2bf(c01.x); o0[5] = f2bf(c01.y); o0[6] = f2bf(c01.z); o0[7] = f2bf(c01.w);
    o1[0] = f2bf(c10.x); o1[1] = f2bf(c10.y); o1[2] = f2bf(c10.z); o1[3] = f2bf(c10.w);
    o1[4] = f2bf(c11.x); o1[5] = f2bf(c11.y); o1[6] = f2bf(c11.z); o1[7] = f2bf(c11.w);
    *(u16x8*)(xurow + kt * 64)      = o0;
    *(u16x8*)(xurow + kt * 64 + 32) = o1;

    // fp32 router partials (rW 24 KB: L1-resident after first wave on the CU)
    #pragma unroll
    for (int e = 0; e < 6; ++e) {
      const float* w = rwb + e * 1024 + kt * 64;
      float4 w00 = *(const float4*)(w + 0);
      float4 w01 = *(const float4*)(w + 4);
      float4 w10 = *(const float4*)(w + 32);
      float4 w11 = *(const float4*)(w + 36);
      lp[e] += c00.x * w00.x + c00.y * w00.y + c00.z * w00.z + c00.w * w00.w
             + c01.x * w01.x + c01.y * w01.y + c01.z * w01.z + c01.w * w01.w
             + c10.x * w10.x + c10.y * w10.y + c10.z * w10.z + c10.w * w10.w
             + c11.x * w11.x + c11.y * w11.y + c11.z * w11.z + c11.w * w11.w;
    }

    // u-MFMA: 16 tokens x 128 u-cols, B straight from W1t (per-kt 16 KB -> L1)
    bf16x8 a0 = __builtin_bit_cast(bf16x8, o0);
    bf16x8 a1 = __builtin_bit_cast(bf16x8, o1);
    #pragma unroll
    for (int n = 0; n < 8; ++n) {
      const u16* wp = wbase + n * 16 * 1024 + kt * 64;
      bf16x8 b0 = *(const bf16x8*)(wp);
      bf16x8 b1 = *(const bf16x8*)(wp + 32);
      acc[n] = __builtin_amdgcn_mfma_f32_16x16x32_bf16(a0, b0, acc[n], 0, 0, 0);
      acc[n] = __builtin_amdgcn_mfma_f32_16x16x32_bf16(a1, b1, acc[n], 0, 0, 0);
    }

    c00 = n00; c01 = n01; c10 = n10; c11 = n11;
  }

  // reduce router partials over the 4 fq-lanes of each token
  #pragma unroll
  for (int e = 0; e < 6; ++e) {
    lp[e] += __shfl_xor(lp[e], 16);
    lp[e] += __shfl_xor(lp[e], 32);
  }

  // fp32 softmax + top-2 (every lane, for its token fr; redundant across fq)
  float wsp[6];
  {
    float lg[6];
    #pragma unroll
    for (int e = 0; e < 6; ++e) lg[e] = lp[e] + rB[e];
    float mx = lg[0];
    #pragma unroll
    for (int e = 1; e < 6; ++e) mx = fmaxf(mx, lg[e]);
    float ex[6], ssum = 0.f;
    #pragma unroll
    for (int e = 0; e < 6; ++e) { ex[e] = __expf(lg[e] - mx); ssum += ex[e]; }
    float inv = 1.0f / ssum;
    int i1 = 0; float v1 = ex[0];     // strict > ascending = lowest-index tie-break
    #pragma unroll
    for (int e = 1; e < 6; ++e) if (ex[e] > v1) { v1 = ex[e]; i1 = e; }
    int i2 = -1; float v2 = -1.0f;
    #pragma unroll
    for (int e = 0; e < 6; ++e) if (e != i1 && ex[e] > v2) { v2 = ex[e]; i2 = e; }
    float g1 = v1 * inv, g2 = v2 * inv;
    float den = g1 + g2 + 1e-6f;
    #pragma unroll
    for (int e = 0; e < 6; ++e)
      wsp[e] = (e == i1) ? g1 / den : ((e == i2) ? g2 / den : 0.0f);
  }

  // redistribute wsp to C-layout rows: lane needs tokens fq*4+g (g=0..3)
  float wg[4][6];
  #pragma unroll
  for (int g = 0; g < 4; ++g)
    #pragma unroll
    for (int e = 0; e < 6; ++e)
      wg[g][e] = __shfl(wsp[e], fq * 4 + g);

  // weighted u -> xu[:,1024:1152]; C/D: col = n*16+fr, row = fq*4+g
  // e = (col-16)>>4 = n-1 (compile-time per unrolled n, fr<16)
  #pragma unroll
  for (int n = 0; n < 8; ++n) {
    int col = n * 16 + fr;
    #pragma unroll
    for (int g = 0; g < 4; ++g) {
      float f = (n == 0) ? 1.0f : ((n < 7) ? wg[g][n - 1] : 0.0f);
      xu[(size_t)(T0 + fq * 4 + g) * XLDA + 1024 + col] = f2bf(acc[n][g] * f);
    }
  }
}

// ==== 256x256 8-phase deep-pipelined GEMM (T1+T2+T3+T4+T5), BK=64, 512 thr ====
#define VMW()  asm volatile("s_waitcnt vmcnt(4)" ::: "memory")
#define VMW0() asm volatile("s_waitcnt vmcnt(0)" ::: "memory")
#define LGW()  asm volatile("s_waitcnt lgkmcnt(0)" ::: "memory")
#define BAR()  __builtin_amdgcn_s_barrier()

__global__ __launch_bounds__(512, 2) void gemm256(
    const u16* __restrict__ A, const u16* __restrict__ B,
    float* __restrict__ out, const float* __restrict__ bias) {
  extern __shared__ char lds[];
  const int lda = XLDA, ldb = XLDA;
  const int tid = threadIdx.x, lane = tid & 63, wid = tid >> 6;
  const int wr = wid >> 2, wcn = wid & 3;        // 2 x 4 wave grid

  int bid = blockIdx.x;
  int xcd = bid & 7, idx = bid >> 3;
  int bx = xcd * 16 + (idx >> 2);
  int by = idx & 3;
  const int rowbase = bx * 256, colbase = by * 256;

  f32x4 acc[8][4];
  #pragma unroll
  for (int m = 0; m < 8; ++m)
    #pragma unroll
    for (int n = 0; n < 4; ++n) acc[m][n] = f32x4{0.f, 0.f, 0.f, 0.f};

  const int l3 = lane >> 3, l7 = lane & 7;
  const int kperm = ((l7 ^ l3) << 3);            // pre-swizzled k elem offset
  const u16* aSrc = A + (size_t)(rowbase + wr * 128 + wcn * 16 + l3) * lda + kperm;
  const int aDst = (wr * 128 + wcn * 16) * 128;
  const int bh = wcn >> 1, bq = wcn & 1;
  const u16* bSrc = B + (size_t)(colbase + bh * 128 + wr * 64 + bq * 16 + l3) * ldb + kperm;
  const int bDst = (bh * 128 + wr * 64 + bq * 16) * 128;

#define STAGE_A(bufp, kt, g) do {                                   \
    const u16* _s = aSrc + (g) * 64 * lda + (kt) * 64;              \
    char* _d = lds + (bufp) * 65536 + aDst + (g) * 64 * 128;        \
    GLOAD_LDS16(_s, _d);                                            \
    GLOAD_LDS16(_s + 8 * lda, _d + 8 * 128);                        \
  } while (0)
#define STAGE_B(bufp, kt, g) do {                                   \
    const u16* _s = bSrc + (g) * 32 * ldb + (kt) * 64;              \
    char* _d = lds + (bufp) * 65536 + 32768 + bDst + (g) * 32 * 128;\
    GLOAD_LDS16(_s, _d);                                            \
    GLOAD_LDS16(_s + 8 * ldb, _d + 8 * 128);                        \
  } while (0)

  const int fr = lane & 15, fq = lane >> 4;
  const int sswz = (lane & 7) << 4;              // (row&7)<<4

  auto LDA_ = [&](int bufp, int mh, bf16x8* a) {
    const char* base = lds + bufp * 65536 + (wr * 128 + mh * 64 + fr) * 128;
    #pragma unroll
    for (int m = 0; m < 4; ++m)
      #pragma unroll
      for (int ks = 0; ks < 2; ++ks)
        a[m * 2 + ks] = *(const bf16x8*)(base + m * 16 * 128 + ((ks * 64 + fq * 16) ^ sswz));
  };
  auto LDB_ = [&](int bufp, int nh, bf16x8* b) {
    const char* base = lds + bufp * 65536 + 32768 + (wcn * 64 + nh * 32 + fr) * 128;
    #pragma unroll
    for (int n = 0; n < 2; ++n)
      #pragma unroll
      for (int ks = 0; ks < 2; ++ks)
        b[n * 2 + ks] = *(const bf16x8*)(base + n * 16 * 128 + ((ks * 64 + fq * 16) ^ sswz));
  };
  auto MF = [&](bf16x8* a, bf16x8* b, int mo, int no) {
    __builtin_amdgcn_s_setprio(1);
    #pragma unroll
    for (int m = 0; m < 4; ++m)
      #pragma unroll
      for (int n = 0; n < 2; ++n)
        #pragma unroll
        for (int ks = 0; ks < 2; ++ks)
          acc[mo + m][no + n] = __builtin_amdgcn_mfma_f32_16x16x32_bf16(
              a[m * 2 + ks], b[n * 2 + ks], acc[mo + m][no + n], 0, 0, 0);
    __builtin_amdgcn_s_setprio(0);
  };

  STAGE_A(0, 0, 0); STAGE_B(0, 0, 0); STAGE_B(0, 0, 1); STAGE_A(0, 0, 1);
  VMW0(); BAR();

  bf16x8 a[8], b0[4], b1[4];
  for (int t = 0; t < 9; ++t) {
    LDA_(0, 0, a); LDB_(0, 0, b0);
    STAGE_A(1, 2 * t + 1, 0);
    VMW(); BAR(); LGW();
    MF(a, b0, 0, 0); BAR();

    LDB_(0, 1, b1);
    STAGE_B(1, 2 * t + 1, 0);
    VMW(); BAR(); LGW();
    MF(a, b1, 0, 2); BAR();

    LDA_(0, 1, a);
    STAGE_B(1, 2 * t + 1, 1);
    VMW(); BAR(); LGW();
    MF(a, b1, 4, 2); BAR();

    STAGE_A(1, 2 * t + 1, 1);
    VMW(); BAR();
    MF(a, b0, 4, 0); BAR();

    LDA_(1, 0, a); LDB_(1, 0, b0);
    if (t < 8) STAGE_A(0, 2 * t + 2, 0);
    VMW(); BAR(); LGW();
    MF(a, b0, 0, 0); BAR();

    LDB_(1, 1, b1);
    if (t < 8) STAGE_B(0, 2 * t + 2, 0);
    VMW(); BAR(); LGW();
    MF(a, b1, 0, 2); BAR();

    LDA_(1, 1, a);
    if (t < 8) STAGE_B(0, 2 * t + 2, 1);
    VMW(); BAR(); LGW();
    MF(a, b1, 4, 2); BAR();

    if (t < 8) STAGE_A(0, 2 * t + 2, 1);
    VMW(); BAR();
    MF(a, b0, 4, 0); BAR();
  }

  int row0 = rowbase + wr * 128 + (fq << 2);
  int col0 = colbase + wcn * 64 + fr;
  #pragma unroll
  for (int n = 0; n < 4; ++n) {
    int col = col0 + n * 16;
    float bv = bias[col];
    #pragma unroll
    for (int m = 0; m < 8; ++m) {
      int rb = row0 + m * 16;
      #pragma unroll
      for (int r = 0; r < 4; ++r)
        out[(size_t)(rb + r) * 1024 + col] = acc[m][n][r] + bv;
    }
  }
#undef STAGE_A
#undef STAGE_B
}

extern "C" void kernel_launch(void* const* d_in, const int* in_sizes, int n_in,
                              void* d_out, int out_size, void* d_ws, size_t ws_size,
                              hipStream_t stream) {
  const float* x       = (const float*)d_in[0];
  const float* baseW   = (const float*)d_in[1];
  const float* baseb   = (const float*)d_in[2];
  const float* sharedA = (const float*)d_in[3];
  const float* sharedB = (const float*)d_in[4];
  const float* routedA = (const float*)d_in[5];
  const float* routedB = (const float*)d_in[6];
  const float* routerW = (const float*)d_in[7];
  const float* routerb = (const float*)d_in[8];
  float* out = (float*)d_out;
  char* ws = (char*)d_ws;
  u16* xu  = (u16*)(ws + WS_XU);
  u16* Wp  = (u16*)(ws + WS_WP);
  u16* W1t = (u16*)(ws + WS_W1T);

  hipFuncSetAttribute((const void*)gemm256,
                      hipFuncAttributeMaxDynamicSharedMemorySize, 131072);

  // (P) pack weights -> Wp, W1t
  pack_weights<<<5120, 256, 0, stream>>>(baseW, sharedA, sharedB, routedA, routedB,
                                         Wp, W1t);
  // (F) wave-autonomous convert + fp32 router + weighted u -> xu[:,0:1152]
  fuse_wave<<<512, 256, 0, stream>>>(x, routerW, routerb, W1t, xu);
  // (C) out = [x|u] @ Wp^T + base_b  (M=32768,N=1024,K=1152), 512 blocks, 8-phase
  gemm256<<<dim3(512, 1), 512, 131072, stream>>>(xu, Wp, out, baseb);
}

// Round 9
// 148.543 us; speedup vs baseline: 1.3988x; 1.3988x over previous
//
#include <hip/hip_runtime.h>
#include <hip/hip_bf16.h>

typedef unsigned short u16;
typedef __attribute__((ext_vector_type(8))) __bf16 bf16x8;
typedef __attribute__((ext_vector_type(8))) unsigned short u16x8;
typedef __attribute__((ext_vector_type(4))) float f32x4;

#define NTOK 32768
#define XLDA 1152           // xu row stride: 1024 x-cols + 128 u-cols
#define WS_XU  0            // u16[NTOK*1152]            = 75,497,472 B
#define WS_WP  75497472     // u16[1024*1152] packed B^T =  2,359,296 B
#define WS_W1T 77856768     // u16[128*1024]  packed A-mats = 262,144 B

static __device__ __forceinline__ u16 f2bf(float f) {
  __hip_bfloat16 h = __float2bfloat16(f);
  return __builtin_bit_cast(u16, h);
}

#define GLOAD_LDS16(g, l)                                                     \
  __builtin_amdgcn_global_load_lds(                                           \
      (const __attribute__((address_space(1))) void*)(g),                     \
      (__attribute__((address_space(3))) void*)(l), 16, 0, 0)

// ---- pack all weight matrices to bf16 in [N][K] (k-contiguous) layout ----
// W1t rows: 0..15 shared_A, 16..111 routed_A, rest 0 (u-cols >=112 are zeroed).
__global__ __launch_bounds__(256) void pack_weights(
    const float* __restrict__ baseW, const float* __restrict__ sharedA,
    const float* __restrict__ sharedB, const float* __restrict__ routedA,
    const float* __restrict__ routedB,
    u16* __restrict__ Wp, u16* __restrict__ W1t) {
  int idx = blockIdx.x * 256 + threadIdx.x;
  const int NWP = 1024 * 1152;
  if (idx < NWP) {
    int o = idx / 1152, k = idx - o * 1152;
    float v;
    if (k < 1024)      v = baseW[o * 1024 + k];
    else if (k < 1040) v = sharedB[o * 16 + (k - 1024)];
    else if (k < 1136) { int c = k - 1040; v = routedB[((c >> 4) * 1024 + o) * 16 + (c & 15)]; }
    else               v = 0.0f;
    Wp[idx] = f2bf(v);
  } else {
    int j = idx - NWP;            // 0 .. 131071
    int n = j >> 10, k = j & 1023;
    float v;
    if (n < 16)       v = sharedA[n * 1024 + k];
    else if (n < 112) v = routedA[(n - 16) * 1024 + k];
    else              v = 0.0f;
    W1t[j] = f2bf(v);
  }
}

// ==== fused: x->bf16 convert + fp32 router/top-2 + u = wsp*(x@W1t^T) ====
// CHAMPION STRUCTURE (155us total): 256 blocks x 256 thr; block b owns tokens
// T0=128b..T0+127. R8 change: x register prefetch one k-tile ahead (the kt+1
// loads issue before the barriers of iteration kt -> full iteration of HBM
// latency cover). No other change vs the 155us version.
__global__ __launch_bounds__(256) void expert_fused(
    const float* __restrict__ x, const float* __restrict__ rW, const float* __restrict__ rB,
    const u16* __restrict__ W1t, u16* __restrict__ xu) {
  __shared__ float rWs[6 * 1024];     // 24 KB: router weights fp32
  __shared__ u16 As[128 * 64];        // 16 KB: converted x tile
  __shared__ u16 Bs[128 * 64];        // 16 KB: W1t tile
  __shared__ float wspS[128][8];      //  4 KB: per-token sparse weights
  const int tid = threadIdx.x, lane = tid & 63, wid = tid >> 6;
  const int T0 = blockIdx.x * 128;

  for (int i = tid; i < 1536; i += 256)
    ((float4*)rWs)[i] = ((const float4*)rW)[i];

  float lp[4][6];
  #pragma unroll
  for (int i = 0; i < 4; ++i)
    #pragma unroll
    for (int e = 0; e < 6; ++e) lp[i][e] = 0.f;
  f32x4 acc[4][4];
  #pragma unroll
  for (int m = 0; m < 4; ++m)
    #pragma unroll
    for (int n = 0; n < 4; ++n) acc[m][n] = f32x4{0.f, 0.f, 0.f, 0.f};

  const int rloc = tid >> 3;          // 0..31 ; row = i*32 + rloc
  const int kc = tid & 7;             // 8-elem k-window
  const int srow = lane >> 3, scol = (lane & 7) * 8;
  const int wr = wid >> 1, wc = wid & 1;

  // x register prefetch: c = current kt window (4 rows x 8 k)
  float4 c[4][2];
  #pragma unroll
  for (int i = 0; i < 4; ++i) {
    const float4* p = (const float4*)(x + (size_t)(T0 + i * 32 + rloc) * 1024 + kc * 8);
    c[i][0] = p[0]; c[i][1] = p[1];
  }

  for (int kt = 0; kt < 16; ++kt) {
    // issue next k-window loads NOW (latency hides under this whole iteration)
    const int ktn = (kt < 15) ? kt + 1 : 15;
    float4 nx[4][2];
    #pragma unroll
    for (int i = 0; i < 4; ++i) {
      const float4* p = (const float4*)(x + (size_t)(T0 + i * 32 + rloc) * 1024 + ktn * 64 + kc * 8);
      nx[i][0] = p[0]; nx[i][1] = p[1];
    }

    __syncthreads();                  // previous iter's LDS reads done
    // stage B tile (W1t 128x64) via global_load_lds
    #pragma unroll
    for (int i = 0; i < 4; ++i) {
      int j = wid * 4 + i;
      GLOAD_LDS16(W1t + (size_t)(j * 8 + srow) * 1024 + kt * 64 + scol, Bs + j * 512);
    }
    // convert current x window -> LDS + global bf16
    #pragma unroll
    for (int i = 0; i < 4; ++i) {
      int r = i * 32 + rloc;
      u16x8 o;
      o[0] = f2bf(c[i][0].x); o[1] = f2bf(c[i][0].y);
      o[2] = f2bf(c[i][0].z); o[3] = f2bf(c[i][0].w);
      o[4] = f2bf(c[i][1].x); o[5] = f2bf(c[i][1].y);
      o[6] = f2bf(c[i][1].z); o[7] = f2bf(c[i][1].w);
      *(u16x8*)&As[r * 64 + kc * 8] = o;
      *(u16x8*)&xu[(size_t)(T0 + r) * XLDA + kt * 64 + kc * 8] = o;
    }
    // fp32 router partials (4 rows share this thread's k-window)
    {
      int kb = kt * 64 + kc * 8;
      #pragma unroll
      for (int e = 0; e < 6; ++e) {
        float4 w0 = *(const float4*)&rWs[e * 1024 + kb];
        float4 w1 = *(const float4*)&rWs[e * 1024 + kb + 4];
        #pragma unroll
        for (int i = 0; i < 4; ++i)
          lp[i][e] += c[i][0].x * w0.x + c[i][0].y * w0.y + c[i][0].z * w0.z + c[i][0].w * w0.w
                    + c[i][1].x * w1.x + c[i][1].y * w1.y + c[i][1].z * w1.z + c[i][1].w * w1.w;
      }
    }
    __syncthreads();                  // As(ds_write)+Bs(gload_lds) drained
    // MFMA: u-tile accumulate
    #pragma unroll
    for (int ks = 0; ks < 2; ++ks) {
      bf16x8 af[4], bfv[4];
      #pragma unroll
      for (int m = 0; m < 4; ++m)
        af[m] = *(const bf16x8*)&As[(wr * 64 + m * 16 + (lane & 15)) * 64 + ks * 32 + (lane >> 4) * 8];
      #pragma unroll
      for (int n = 0; n < 4; ++n)
        bfv[n] = *(const bf16x8*)&Bs[(wc * 64 + n * 16 + (lane & 15)) * 64 + ks * 32 + (lane >> 4) * 8];
      #pragma unroll
      for (int m = 0; m < 4; ++m)
        #pragma unroll
        for (int n = 0; n < 4; ++n)
          acc[m][n] = __builtin_amdgcn_mfma_f32_16x16x32_bf16(af[m], bfv[n], acc[m][n], 0, 0, 0);
    }
    // rotate prefetch registers (all indices compile-time; stays in VGPRs)
    #pragma unroll
    for (int i = 0; i < 4; ++i) { c[i][0] = nx[i][0]; c[i][1] = nx[i][1]; }
  }

  // reduce router partials over the 8 k-window lanes (bits 0..2 of lane)
  #pragma unroll
  for (int m = 1; m <= 4; m <<= 1)
    #pragma unroll
    for (int i = 0; i < 4; ++i)
      #pragma unroll
      for (int e = 0; e < 6; ++e)
        lp[i][e] += __shfl_xor(lp[i][e], m);

  if ((lane & 7) == 0) {
    #pragma unroll
    for (int i = 0; i < 4; ++i) {
      int r = i * 32 + rloc;
      float lg[6];
      #pragma unroll
      for (int e = 0; e < 6; ++e) lg[e] = lp[i][e] + rB[e];
      float mx = lg[0];
      #pragma unroll
      for (int e = 1; e < 6; ++e) mx = fmaxf(mx, lg[e]);
      float ex[6], ssum = 0.f;
      #pragma unroll
      for (int e = 0; e < 6; ++e) { ex[e] = __expf(lg[e] - mx); ssum += ex[e]; }
      float inv = 1.0f / ssum;
      int i1 = 0; float v1 = ex[0];   // strict > ascending = lowest-index tie-break
      #pragma unroll
      for (int e = 1; e < 6; ++e) if (ex[e] > v1) { v1 = ex[e]; i1 = e; }
      int i2 = -1; float v2 = -1.0f;
      #pragma unroll
      for (int e = 0; e < 6; ++e) if (e != i1 && ex[e] > v2) { v2 = ex[e]; i2 = e; }
      float g1 = v1 * inv, g2 = v2 * inv;
      float den = g1 + g2 + 1e-6f;
      #pragma unroll
      for (int e = 0; e < 6; ++e)
        wspS[r][e] = (e == i1) ? g1 / den : ((e == i2) ? g2 / den : 0.0f);
    }
  }
  __syncthreads();

  // epilogue: weighted u -> xu[:,1024:1152]; C/D: col=lane&15, row=(lane>>4)*4+reg
  int row0 = wr * 64 + ((lane >> 4) << 2);
  int col0 = wc * 64 + (lane & 15);
  #pragma unroll
  for (int n = 0; n < 4; ++n) {
    int col = col0 + n * 16;          // 0..127
    int e = (col - 16) >> 4;
    #pragma unroll
    for (int m = 0; m < 4; ++m) {
      #pragma unroll
      for (int r = 0; r < 4; ++r) {
        int rl = row0 + m * 16 + r;
        float f = (col < 16) ? 1.0f : ((col < 112) ? wspS[rl][e] : 0.0f);
        xu[(size_t)(T0 + rl) * XLDA + 1024 + col] = f2bf(acc[m][n][r] * f);
      }
    }
  }
}

// ==== 256x256 8-phase deep-pipelined GEMM (T1+T2+T3+T4+T5), BK=64, 512 thr ====
#define VMW()  asm volatile("s_waitcnt vmcnt(4)" ::: "memory")
#define VMW0() asm volatile("s_waitcnt vmcnt(0)" ::: "memory")
#define LGW()  asm volatile("s_waitcnt lgkmcnt(0)" ::: "memory")
#define BAR()  __builtin_amdgcn_s_barrier()

__global__ __launch_bounds__(512, 2) void gemm256(
    const u16* __restrict__ A, const u16* __restrict__ B,
    float* __restrict__ out, const float* __restrict__ bias) {
  extern __shared__ char lds[];
  const int lda = XLDA, ldb = XLDA;
  const int tid = threadIdx.x, lane = tid & 63, wid = tid >> 6;
  const int wr = wid >> 2, wcn = wid & 3;        // 2 x 4 wave grid

  int bid = blockIdx.x;
  int xcd = bid & 7, idx = bid >> 3;
  int bx = xcd * 16 + (idx >> 2);
  int by = idx & 3;
  const int rowbase = bx * 256, colbase = by * 256;

  f32x4 acc[8][4];
  #pragma unroll
  for (int m = 0; m < 8; ++m)
    #pragma unroll
    for (int n = 0; n < 4; ++n) acc[m][n] = f32x4{0.f, 0.f, 0.f, 0.f};

  const int l3 = lane >> 3, l7 = lane & 7;
  const int kperm = ((l7 ^ l3) << 3);            // pre-swizzled k elem offset
  const u16* aSrc = A + (size_t)(rowbase + wr * 128 + wcn * 16 + l3) * lda + kperm;
  const int aDst = (wr * 128 + wcn * 16) * 128;
  const int bh = wcn >> 1, bq = wcn & 1;
  const u16* bSrc = B + (size_t)(colbase + bh * 128 + wr * 64 + bq * 16 + l3) * ldb + kperm;
  const int bDst = (bh * 128 + wr * 64 + bq * 16) * 128;

#define STAGE_A(bufp, kt, g) do {                                   \
    const u16* _s = aSrc + (g) * 64 * lda + (kt) * 64;              \
    char* _d = lds + (bufp) * 65536 + aDst + (g) * 64 * 128;        \
    GLOAD_LDS16(_s, _d);                                            \
    GLOAD_LDS16(_s + 8 * lda, _d + 8 * 128);                        \
  } while (0)
#define STAGE_B(bufp, kt, g) do {                                   \
    const u16* _s = bSrc + (g) * 32 * ldb + (kt) * 64;              \
    char* _d = lds + (bufp) * 65536 + 32768 + bDst + (g) * 32 * 128;\
    GLOAD_LDS16(_s, _d);                                            \
    GLOAD_LDS16(_s + 8 * ldb, _d + 8 * 128);                        \
  } while (0)

  const int fr = lane & 15, fq = lane >> 4;
  const int sswz = (lane & 7) << 4;              // (row&7)<<4

  auto LDA_ = [&](int bufp, int mh, bf16x8* a) {
    const char* base = lds + bufp * 65536 + (wr * 128 + mh * 64 + fr) * 128;
    #pragma unroll
    for (int m = 0; m < 4; ++m)
      #pragma unroll
      for (int ks = 0; ks < 2; ++ks)
        a[m * 2 + ks] = *(const bf16x8*)(base + m * 16 * 128 + ((ks * 64 + fq * 16) ^ sswz));
  };
  auto LDB_ = [&](int bufp, int nh, bf16x8* b) {
    const char* base = lds + bufp * 65536 + 32768 + (wcn * 64 + nh * 32 + fr) * 128;
    #pragma unroll
    for (int n = 0; n < 2; ++n)
      #pragma unroll
      for (int ks = 0; ks < 2; ++ks)
        b[n * 2 + ks] = *(const bf16x8*)(base + n * 16 * 128 + ((ks * 64 + fq * 16) ^ sswz));
  };
  auto MF = [&](bf16x8* a, bf16x8* b, int mo, int no) {
    __builtin_amdgcn_s_setprio(1);
    #pragma unroll
    for (int m = 0; m < 4; ++m)
      #pragma unroll
      for (int n = 0; n < 2; ++n)
        #pragma unroll
        for (int ks = 0; ks < 2; ++ks)
          acc[mo + m][no + n] = __builtin_amdgcn_mfma_f32_16x16x32_bf16(
              a[m * 2 + ks], b[n * 2 + ks], acc[mo + m][no + n], 0, 0, 0);
    __builtin_amdgcn_s_setprio(0);
  };

  STAGE_A(0, 0, 0); STAGE_B(0, 0, 0); STAGE_B(0, 0, 1); STAGE_A(0, 0, 1);
  VMW0(); BAR();

  bf16x8 a[8], b0[4], b1[4];
  for (int t = 0; t < 9; ++t) {
    LDA_(0, 0, a); LDB_(0, 0, b0);
    STAGE_A(1, 2 * t + 1, 0);
    VMW(); BAR(); LGW();
    MF(a, b0, 0, 0); BAR();

    LDB_(0, 1, b1);
    STAGE_B(1, 2 * t + 1, 0);
    VMW(); BAR(); LGW();
    MF(a, b1, 0, 2); BAR();

    LDA_(0, 1, a);
    STAGE_B(1, 2 * t + 1, 1);
    VMW(); BAR(); LGW();
    MF(a, b1, 4, 2); BAR();

    STAGE_A(1, 2 * t + 1, 1);
    VMW(); BAR();
    MF(a, b0, 4, 0); BAR();

    LDA_(1, 0, a); LDB_(1, 0, b0);
    if (t < 8) STAGE_A(0, 2 * t + 2, 0);
    VMW(); BAR(); LGW();
    MF(a, b0, 0, 0); BAR();

    LDB_(1, 1, b1);
    if (t < 8) STAGE_B(0, 2 * t + 2, 0);
    VMW(); BAR(); LGW();
    MF(a, b1, 0, 2); BAR();

    LDA_(1, 1, a);
    if (t < 8) STAGE_B(0, 2 * t + 2, 1);
    VMW(); BAR(); LGW();
    MF(a, b1, 4, 2); BAR();

    if (t < 8) STAGE_A(0, 2 * t + 2, 1);
    VMW(); BAR();
    MF(a, b0, 4, 0); BAR();
  }

  int row0 = rowbase + wr * 128 + (fq << 2);
  int col0 = colbase + wcn * 64 + fr;
  #pragma unroll
  for (int n = 0; n < 4; ++n) {
    int col = col0 + n * 16;
    float bv = bias[col];
    #pragma unroll
    for (int m = 0; m < 8; ++m) {
      int rb = row0 + m * 16;
      #pragma unroll
      for (int r = 0; r < 4; ++r)
        out[(size_t)(rb + r) * 1024 + col] = acc[m][n][r] + bv;
    }
  }
#undef STAGE_A
#undef STAGE_B
}

extern "C" void kernel_launch(void* const* d_in, const int* in_sizes, int n_in,
                              void* d_out, int out_size, void* d_ws, size_t ws_size,
                              hipStream_t stream) {
  const float* x       = (const float*)d_in[0];
  const float* baseW   = (const float*)d_in[1];
  const float* baseb   = (const float*)d_in[2];
  const float* sharedA = (const float*)d_in[3];
  const float* sharedB = (const float*)d_in[4];
  const float* routedA = (const float*)d_in[5];
  const float* routedB = (const float*)d_in[6];
  const float* routerW = (const float*)d_in[7];
  const float* routerb = (const float*)d_in[8];
  float* out = (float*)d_out;
  char* ws = (char*)d_ws;
  u16* xu  = (u16*)(ws + WS_XU);
  u16* Wp  = (u16*)(ws + WS_WP);
  u16* W1t = (u16*)(ws + WS_W1T);

  hipFuncSetAttribute((const void*)gemm256,
                      hipFuncAttributeMaxDynamicSharedMemorySize, 131072);

  // (P) pack weights -> Wp, W1t
  pack_weights<<<5120, 256, 0, stream>>>(baseW, sharedA, sharedB, routedA, routedB,
                                         Wp, W1t);
  // (F) fused convert + fp32 router + weighted u -> xu[:,0:1152]  (champion + prefetch)
  expert_fused<<<256, 256, 0, stream>>>(x, routerW, routerb, W1t, xu);
  // (C) out = [x|u] @ Wp^T + base_b  (M=32768,N=1024,K=1152), 512 blocks, 8-phase
  gemm256<<<dim3(512, 1), 512, 131072, stream>>>(xu, Wp, out, baseb);
}